// Round 7
// baseline (123.606 us; speedup 1.0000x reference)
//
#include <hip/hip_runtime.h>

#define KN 8192

// LESSONS:
//  R5: cg::grid_group::sync() ~150us/sync on gfx950 -- never use it here.
//  R4/R6: 528-deep same-address device atomicAdd fan-in adds ~5us retire
//         tail -- use distinct-line slot stores + leader collection instead.

constexpr int UT   = 1024;       // u per block, phase 1 (4/thread)
constexpr int VC   = 128;        // v per block, phase 1
constexpr int NVT  = KN / VC;    // 64 v-tiles
constexpr int GRID = 1024;       // 4 blocks/CU, co-resident (cooperative launch)
constexpr int SLOT_STRIDE = 16;  // 64 B per slot: one cache line each, no fan-in

constexpr unsigned int TOK1  = 0x11111111u;  // barrier-1 arrival token
constexpr unsigned int TOK2  = 0x22222222u;  // barrier-2 arrival token
constexpr unsigned int MARK3 = 0x40000000u;  // phase-3 publish: MARK3 | count (count < 2^17)
// ws is re-poisoned to 0xAAAAAAAA before every call, so stale tokens never leak.

// Monotone float->uint transform packed with index: lexicographic (value,idx)
// order == jnp stable argsort order. 64-bit needed: ~1 expected f32 collision
// among 8192 N(0,1) samples would break the rank->scatter inverse.
__device__ __forceinline__ unsigned long long make_key(float x, int idx) {
    unsigned int u = __float_as_uint(x);
    u ^= (unsigned int)((int)u >> 31) | 0x80000000u;
    return ((unsigned long long)u << 13) | (unsigned int)idx;
}

__device__ __forceinline__ void slot_store(unsigned int* slots, int i, unsigned int v) {
    __hip_atomic_store(&slots[i * SLOT_STRIDE], v, __ATOMIC_RELAXED, __HIP_MEMORY_SCOPE_AGENT);
}
__device__ __forceinline__ unsigned int slot_load(unsigned int* slots, int i) {
    return __hip_atomic_load(&slots[i * SLOT_STRIDE], __ATOMIC_RELAXED, __HIP_MEMORY_SCOPE_AGENT);
}

// ---------------------------------------------------------------------------
// One cooperative kernel, 1024 blocks x 256 threads, hand-rolled barriers.
// Phase 1 (all 1024): brute-force rank partials (ushort, disjoint slices).
// B1: all arrive (slot=TOK1); block 0 polls 1024 slots, sets rel1.
//     Blocks 528..1023 exit after arrival (not needed later).
// Phase 2 (blocks 0..63): reduce 64 partials/u -> rank_a[u] (arr0) or
//     scatter b[r]=u (arr1).
// B2: blocks 0..63 arrive (slot=TOK2); block 0 polls 64 slots, sets rel2.
//     Blocks 64..527 wait on rel2 directly (rel2 implies rel1).
// Phase 3 (blocks 0..527): inversion count of e[k]=b[rank_a[k]] on
//     triangular 256-tiles; publish MARK3|cnt in own slot.
// Collect (block 0): poll 528 slots for MARK3, sum, write output.
// ---------------------------------------------------------------------------
__global__ __launch_bounds__(256) void kendall_fused(const float* __restrict__ X,
                                                     const float* __restrict__ Xh,
                                                     unsigned short* __restrict__ part,
                                                     int* __restrict__ rank_a,
                                                     int* __restrict__ b,
                                                     unsigned int* __restrict__ slots,
                                                     unsigned int* __restrict__ rel,
                                                     float* __restrict__ out) {
    int blk = blockIdx.x;
    int tid = threadIdx.x;

    __shared__ unsigned long long tile[VC];
    __shared__ int le[256];
    __shared__ int red[4];

    // ---------------- Phase 1: rank partials ----------------
    {
        int arr = blk & 1;
        int vt  = (blk >> 1) & (NVT - 1);
        int ut  = blk >> 7;
        const float* src = arr ? Xh : X;

        int u0 = ut * UT + tid;
        unsigned long long ku0 = make_key(src[u0],       u0);
        unsigned long long ku1 = make_key(src[u0 + 256], u0 + 256);
        unsigned long long ku2 = make_key(src[u0 + 512], u0 + 512);
        unsigned long long ku3 = make_key(src[u0 + 768], u0 + 768);

        if (tid < VC) {
            int v = vt * VC + tid;
            tile[tid] = make_key(src[v], v);
        }
        __syncthreads();

        int c0 = 0, c1 = 0, c2 = 0, c3 = 0;
#pragma unroll 8
        for (int jj = 0; jj < VC; ++jj) {
            unsigned long long kv = tile[jj];   // wave-uniform -> LDS broadcast
            c0 += (kv < ku0);
            c1 += (kv < ku1);
            c2 += (kv < ku2);
            c3 += (kv < ku3);
        }

        int base = (arr * NVT + vt) * KN + u0;  // disjoint per block
        part[base]       = (unsigned short)c0;
        part[base + 256] = (unsigned short)c1;
        part[base + 512] = (unsigned short)c2;
        part[base + 768] = (unsigned short)c3;
    }

    // ---------------- Barrier 1: arrive ----------------
    __syncthreads();
    if (tid == 0) { __threadfence(); slot_store(slots, blk, TOK1); }
    if (blk >= 528) return;                    // done: part flushed + token stored

    if (blk == 0) {
        // leader: wait for all 1024 arrivals, then release rel1
        for (int j = tid; j < GRID; j += 256)
            while (slot_load(slots, j) != TOK1) __builtin_amdgcn_s_sleep(2);
        __syncthreads();
        if (tid == 0) {
            __threadfence();                   // acquire for own phase-2 reads
            __hip_atomic_store(&rel[0], TOK1, __ATOMIC_RELAXED, __HIP_MEMORY_SCOPE_AGENT);
        }
        __syncthreads();
    } else if (blk < 64) {
        // phase-2 workers wait on rel1
        if (tid == 0) {
            while (__hip_atomic_load(&rel[0], __ATOMIC_RELAXED, __HIP_MEMORY_SCOPE_AGENT) != TOK1)
                __builtin_amdgcn_s_sleep(2);
            __threadfence();                   // acquire: invalidate stale caches
        }
        __syncthreads();
    }
    // blocks 64..527 skip rel1 and wait on rel2 below (rel2 implies rel1)

    // ---------------- Phase 2: reduce + scatter (blocks 0..63) ----------------
    if (blk < 64) {
        int t = blk * 256 + tid;               // 0..16383
        int arr = t >> 13;
        int u   = t & (KN - 1);
        const unsigned short* p = part + (arr * NVT) * KN + u;
        int r = 0;
#pragma unroll 8
        for (int vt = 0; vt < NVT; ++vt) r += p[vt * KN];   // coalesced
        if (arr == 0) rank_a[u] = r;
        else          b[r] = u;

        // ---------------- Barrier 2: arrive ----------------
        __syncthreads();
        if (tid == 0) { __threadfence(); slot_store(slots, blk, TOK2); }
    }

    if (blk == 0) {
        for (int j = tid; j < 64; j += 256)    // only tid<64 poll
            while (slot_load(slots, j) != TOK2) __builtin_amdgcn_s_sleep(2);
        __syncthreads();
        if (tid == 0) {
            __threadfence();
            __hip_atomic_store(&rel[SLOT_STRIDE], TOK2, __ATOMIC_RELAXED, __HIP_MEMORY_SCOPE_AGENT);
        }
        __syncthreads();
    } else {
        if (tid == 0) {
            while (__hip_atomic_load(&rel[SLOT_STRIDE], __ATOMIC_RELAXED, __HIP_MEMORY_SCOPE_AGENT) != TOK2)
                __builtin_amdgcn_s_sleep(2);
            __threadfence();                   // acquire
        }
        __syncthreads();
    }

    // ---------------- Phase 3: inversion count (blocks 0..527) ----------------
    // e[k] = b[rank_a[k]], gathered on the fly; inv(e) == ndisordered/2.
    unsigned int blkCnt;
    {
        constexpr int TS = 256;
        constexpr int T  = KN / TS;            // 32; 32*33/2 = 528 tile pairs

        int p = 0, rem = blk;
        while (rem >= T - p) { rem -= T - p; ++p; }
        int q = p + rem;                       // p <= q

        int ek = b[rank_a[p * TS + tid]];
        le[tid] = b[rank_a[q * TS + tid]];
        __syncthreads();

        int cnt = 0;
        if (p == q) {
            for (int j = tid + 1; j < TS; ++j) cnt += (ek > le[j]);
        } else {
            const int4* le4 = (const int4*)le;
#pragma unroll 8
            for (int j4 = 0; j4 < TS / 4; ++j4) {
                int4 v = le4[j4];              // wave-uniform -> ds_read_b128
                cnt += (ek > v.x) + (ek > v.y) + (ek > v.z) + (ek > v.w);
            }
        }

        for (int off = 32; off; off >>= 1) cnt += __shfl_down(cnt, off);
        if ((tid & 63) == 0) red[tid >> 6] = cnt;
        __syncthreads();
        blkCnt = (unsigned int)(red[0] + red[1] + red[2] + red[3]);
    }
    if (tid == 0) slot_store(slots, blk, MARK3 | blkCnt);  // value rides in the slot
    if (blk != 0) return;

    // ---------------- Collect + finalize (block 0) ----------------
    {
        __syncthreads();                       // red[] reuse below
        int sum = 0;
        for (int j = tid; j < 528; j += 256) {
            unsigned int v;
            while ((((v = slot_load(slots, j)) & 0xFF000000u)) != MARK3)
                __builtin_amdgcn_s_sleep(2);
            sum += (int)(v & 0x00FFFFFFu);
        }
        for (int off = 32; off; off >>= 1) sum += __shfl_down(sum, off);
        if ((tid & 63) == 0) red[tid >> 6] = sum;
        __syncthreads();
        if (tid == 0) {
            float D = (float)(red[0] + red[1] + red[2] + red[3]);  // < 2^25: exact
            out[0] = 2.0f * D / ((float)KN * (float)(KN - 1));
        }
    }
}

// ---------------------------------------------------------------------------
// Workspace layout (bytes); every word written before read each call:
//   0        : part[2*64*8192] ushort  (2 MiB)
//   2097152  : rank_a[8192] int
//   2129920  : b[8192] int
//   2162688  : slots[1024 * 16] uint   (64 KiB, one line per block)
//   2228224  : rel[32] uint            (rel1 @ +0, rel2 @ +64B)
// ---------------------------------------------------------------------------
extern "C" void kernel_launch(void* const* d_in, const int* in_sizes, int n_in,
                              void* d_out, int out_size, void* d_ws, size_t ws_size,
                              hipStream_t stream) {
    const float* X  = (const float*)d_in[0];
    const float* Xh = (const float*)d_in[1];

    char* ws = (char*)d_ws;
    unsigned short* part = (unsigned short*)(ws);
    int* rank_a          = (int*)(ws + 2097152);
    int* b               = (int*)(ws + 2129920);
    unsigned int* slots  = (unsigned int*)(ws + 2162688);
    unsigned int* rel    = (unsigned int*)(ws + 2228224);
    float* outp          = (float*)d_out;

    void* args[] = { (void*)&X, (void*)&Xh, (void*)&part, (void*)&rank_a,
                     (void*)&b, (void*)&slots, (void*)&rel, (void*)&outp };
    hipLaunchCooperativeKernel((const void*)kendall_fused, dim3(GRID), dim3(256),
                               args, 0, stream);
}

// Round 8
// 84.335 us; speedup vs baseline: 1.4657x; 1.4657x over previous
//
#include <hip/hip_runtime.h>

#define KN 8192

// LESSONS (measured this session):
//  R5: cg::grid_group::sync() ~150us/sync on gfx950 -- never.
//  R4/R6: 100s-deep same-address device atomicAdd fan-in ~ +5us tail.
//  R7: hipLaunchCooperativeKernel graph nodes add ~20us+ replay overhead;
//      a 1024-arrival hand barrier is worse than a kernel boundary.
//  => kernel boundary for the WIDE barrier; hand-rolled slot barrier (64
//     arrivals, distinct cache lines) inside a REGULAR launch for the narrow
//     one. 528 blocks x 4 waves << 2048-wave capacity => co-resident, no
//     deadlock regardless of dispatch order.

constexpr int UT  = 1024;        // u per block, K1 (4/thread)
constexpr int VC  = 128;         // v per block, K1
constexpr int NVT = KN / VC;     // 64 v-tiles
constexpr int SLOT_STRIDE = 16;  // 64 B per slot: one cache line each

constexpr unsigned int TOK2  = 0x22222222u;  // reduce-done token
constexpr unsigned int MARK3 = 0x40000000u;  // inv partial: MARK3 | cnt (cnt < 2^24)
// ws is re-poisoned to 0xAAAAAAAA before every call: poison never matches a
// token, so no zeroing pass is needed and no state leaks between calls.

// Monotone float->uint transform packed with index: lexicographic (value,idx)
// order == jnp stable argsort order. 64-bit needed: ~1 expected f32 value
// collision among 8192 N(0,1) samples would break the rank->scatter inverse.
__device__ __forceinline__ unsigned long long make_key(float x, int idx) {
    unsigned int u = __float_as_uint(x);
    u ^= (unsigned int)((int)u >> 31) | 0x80000000u;
    return ((unsigned long long)u << 13) | (unsigned int)idx;
}

__device__ __forceinline__ void slot_store(unsigned int* slots, int i, unsigned int v) {
    __hip_atomic_store(&slots[i * SLOT_STRIDE], v, __ATOMIC_RELAXED, __HIP_MEMORY_SCOPE_AGENT);
}
__device__ __forceinline__ unsigned int slot_load(unsigned int* slots, int i) {
    return __hip_atomic_load(&slots[i * SLOT_STRIDE], __ATOMIC_RELAXED, __HIP_MEMORY_SCOPE_AGENT);
}

// ---------------------------------------------------------------------------
// K1: partial ranks, brute force, no atomics.
// rank[u] = #{ v : key[v] < key[u] }  (keys distinct)
// grid = 8 u-tiles x 64 v-tiles x 2 arrays = 1024 blocks of 256 threads.
// part is ushort (counts <= VC = 128), disjoint slice per block.
// ---------------------------------------------------------------------------
__global__ __launch_bounds__(256) void rank_partial(const float* __restrict__ X,
                                                    const float* __restrict__ Xh,
                                                    unsigned short* __restrict__ part) {
    int blk = blockIdx.x;
    int arr = blk & 1;
    int vt  = (blk >> 1) & (NVT - 1);
    int ut  = blk >> 7;
    const float* src = arr ? Xh : X;

    int tid = threadIdx.x;
    int u0 = ut * UT + tid;

    unsigned long long ku0 = make_key(src[u0],       u0);
    unsigned long long ku1 = make_key(src[u0 + 256], u0 + 256);
    unsigned long long ku2 = make_key(src[u0 + 512], u0 + 512);
    unsigned long long ku3 = make_key(src[u0 + 768], u0 + 768);

    __shared__ unsigned long long tile[VC];
    if (tid < VC) {
        int v = vt * VC + tid;
        tile[tid] = make_key(src[v], v);
    }
    __syncthreads();

    int c0 = 0, c1 = 0, c2 = 0, c3 = 0;
#pragma unroll 8
    for (int jj = 0; jj < VC; ++jj) {
        unsigned long long kv = tile[jj];   // wave-uniform -> LDS broadcast
        c0 += (kv < ku0);
        c1 += (kv < ku1);
        c2 += (kv < ku2);
        c3 += (kv < ku3);
    }

    int base = (arr * NVT + vt) * KN + u0;  // disjoint per block, coalesced
    part[base]       = (unsigned short)c0;
    part[base + 256] = (unsigned short)c1;
    part[base + 512] = (unsigned short)c2;
    part[base + 768] = (unsigned short)c3;
}

// ---------------------------------------------------------------------------
// K2 (regular launch, 528 blocks x 256):
//  stage A (blocks 0..63): reduce 64 partials/u -> rank_a[u] (arr0) or
//          scatter b[r]=u (arr1); publish TOK2 in own slot (own cache line).
//  barrier: block 0 polls the 64 slots, sets rel[0]; blocks 1..527 poll rel.
//  stage B (all 528): inversion count of e[k]=b[rank_a[k]] on triangular
//          256-tiles; publish MARK3|cnt in own slot (no atomic fan-in).
//  collect: block 0 polls 528 slots, sums, writes out = 2D/(n(n-1)).
// ---------------------------------------------------------------------------
__global__ __launch_bounds__(256) void reduce_inv_fused(const unsigned short* __restrict__ part,
                                                        int* __restrict__ rank_a,
                                                        int* __restrict__ b,
                                                        unsigned int* __restrict__ slots,
                                                        unsigned int* __restrict__ rel,
                                                        float* __restrict__ out) {
    int blk = blockIdx.x;
    int tid = threadIdx.x;

    __shared__ int le[256];
    __shared__ int red[4];

    // ---- stage A: reduce + scatter (blocks 0..63) ----
    if (blk < 64) {
        int t = blk * 256 + tid;               // 0..16383
        int arr = t >> 13;
        int u   = t & (KN - 1);
        const unsigned short* p = part + (arr * NVT) * KN + u;
        int r = 0;
#pragma unroll 8
        for (int vt = 0; vt < NVT; ++vt) r += p[vt * KN];   // coalesced
        if (arr == 0) rank_a[u] = r;
        else          b[r] = u;
        __syncthreads();
        if (tid == 0) { __threadfence(); slot_store(slots, blk, TOK2); }
    }

    // ---- narrow barrier: 64 arrivals ----
    if (blk == 0) {
        for (int j = tid; j < 64; j += 256)    // tids 0..63 poll one slot each
            while (slot_load(slots, j) != TOK2) __builtin_amdgcn_s_sleep(2);
        __syncthreads();
        if (tid == 0) {
            __threadfence();
            __hip_atomic_store(&rel[0], TOK2, __ATOMIC_RELAXED, __HIP_MEMORY_SCOPE_AGENT);
        }
        __syncthreads();
    } else {
        if (tid == 0) {
            while (__hip_atomic_load(&rel[0], __ATOMIC_RELAXED, __HIP_MEMORY_SCOPE_AGENT) != TOK2)
                __builtin_amdgcn_s_sleep(2);
            __threadfence();                   // acquire: see rank_a/b
        }
        __syncthreads();
    }

    // ---- stage B: inversion count (all 528 blocks) ----
    unsigned int blkCnt;
    {
        constexpr int TS = 256;
        constexpr int T  = KN / TS;            // 32; 32*33/2 = 528 tile pairs

        int p = 0, rem = blk;
        while (rem >= T - p) { rem -= T - p; ++p; }   // wave-uniform decode
        int q = p + rem;                              // p <= q

        int ek = b[rank_a[p * TS + tid]];             // e gathered on the fly
        le[tid] = b[rank_a[q * TS + tid]];
        __syncthreads();

        int cnt = 0;
        if (p == q) {
            for (int j = tid + 1; j < TS; ++j) cnt += (ek > le[j]);
        } else {
            const int4* le4 = (const int4*)le;
#pragma unroll 8
            for (int j4 = 0; j4 < TS / 4; ++j4) {
                int4 v = le4[j4];              // wave-uniform -> ds_read_b128
                cnt += (ek > v.x) + (ek > v.y) + (ek > v.z) + (ek > v.w);
            }
        }

        for (int off = 32; off; off >>= 1) cnt += __shfl_down(cnt, off);
        if ((tid & 63) == 0) red[tid >> 6] = cnt;
        __syncthreads();
        blkCnt = (unsigned int)(red[0] + red[1] + red[2] + red[3]);
    }
    if (tid == 0) slot_store(slots, blk, MARK3 | blkCnt);
    if (blk != 0) return;

    // ---- collect + finalize (block 0) ----
    __syncthreads();
    int sum = 0;
    for (int j = tid; j < 528; j += 256) {     // ~2 slots/thread
        unsigned int v;
        while (((v = slot_load(slots, j)) & 0xFF000000u) != MARK3)
            __builtin_amdgcn_s_sleep(2);
        sum += (int)(v & 0x00FFFFFFu);
    }
    for (int off = 32; off; off >>= 1) sum += __shfl_down(sum, off);
    if ((tid & 63) == 0) red[tid >> 6] = sum;
    __syncthreads();
    if (tid == 0) {
        float D = (float)(red[0] + red[1] + red[2] + red[3]);   // < 2^25: exact
        out[0] = 2.0f * D / ((float)KN * (float)(KN - 1));
    }
}

// ---------------------------------------------------------------------------
// Workspace layout (bytes); every word written before read each call, and
// tokens can never equal the 0xAAAAAAAA poison -> no memset needed.
//   0        : part[2*64*8192] ushort  (2 MiB)
//   2097152  : rank_a[8192] int
//   2129920  : b[8192] int
//   2162688  : slots[528 * 16] uint    (one cache line per block)
//   2228224  : rel[16] uint
// ---------------------------------------------------------------------------
extern "C" void kernel_launch(void* const* d_in, const int* in_sizes, int n_in,
                              void* d_out, int out_size, void* d_ws, size_t ws_size,
                              hipStream_t stream) {
    const float* X  = (const float*)d_in[0];
    const float* Xh = (const float*)d_in[1];

    char* ws = (char*)d_ws;
    unsigned short* part = (unsigned short*)(ws);
    int* rank_a          = (int*)(ws + 2097152);
    int* b               = (int*)(ws + 2129920);
    unsigned int* slots  = (unsigned int*)(ws + 2162688);
    unsigned int* rel    = (unsigned int*)(ws + 2228224);

    rank_partial   <<<dim3(1024), dim3(256), 0, stream>>>(X, Xh, part);
    reduce_inv_fused<<<dim3(528), dim3(256), 0, stream>>>(part, rank_a, b, slots, rel,
                                                          (float*)d_out);
}